// Round 12
// baseline (311.790 us; speedup 1.0000x reference)
//
#include <hip/hip_runtime.h>
#include <hip/hip_fp16.h>

typedef _Float16 f16;
typedef f16 f16x4 __attribute__((ext_vector_type(4)));
typedef f16 f16x8 __attribute__((ext_vector_type(8)));
typedef float f32x4 __attribute__((ext_vector_type(4)));

#define MFMA16(a, b, c) __builtin_amdgcn_mfma_f32_16x16x32_f16(a, b, c, 0, 0, 0)

static constexpr int Bn = 2, Sn = 2048, Dn = 1024, Hn = 16, HDn = 64;
static constexpr int Mn = Bn * Sn; // 4096
static constexpr float kQScale = 0.125f * 1.44269504088896f; // 1/sqrt(64) * log2(e)

__device__ inline void gload_lds16(const void* g, void* l) {
    __builtin_amdgcn_global_load_lds((const __attribute__((address_space(1))) void*)g,
                                     (__attribute__((address_space(3))) void*)l,
                                     16, 0, 0);
}

// T2 both-sides swizzle for [rows][64] f16 LDS tiles (row = 8 chunks of 16B).
__device__ inline int swz(int row, int chunk) {
    return row * 64 + ((chunk ^ (row & 7)) * 8);
}

// ---------------------------------------------------------------------------
// One-shot f32->f16 conversion of q,k,v and Wq,Wk,Wv,Wo.
// ---------------------------------------------------------------------------
__global__ __launch_bounds__(256) void convert_all(
    const float* __restrict__ q, const float* __restrict__ k, const float* __restrict__ v,
    const float* __restrict__ wq, const float* __restrict__ wk, const float* __restrict__ wv,
    const float* __restrict__ wo,
    f16* qo, f16* ko, f16* vo, f16* wqo, f16* wko, f16* wvo, f16* woo) {
    const int c = blockIdx.x * 256 + threadIdx.x;
    const float* src;
    f16* dst;
    int off;
    if (c < 3 * 524288) {
        const int t = c >> 19;
        off = c & 524287;
        src = (t == 0) ? q : (t == 1) ? k : v;
        dst = (t == 0) ? qo : (t == 1) ? ko : vo;
    } else {
        const int c2 = c - 3 * 524288;
        const int t = c2 >> 17;
        off = c2 & 131071;
        src = (t == 0) ? wq : (t == 1) ? wk : (t == 2) ? wv : wo;
        dst = (t == 0) ? wqo : (t == 1) ? wko : (t == 2) ? wvo : woo;
    }
    const float4 a = ((const float4*)src)[off * 2];
    const float4 b = ((const float4*)src)[off * 2 + 1];
    f16x8 r = {(f16)a.x, (f16)a.y, (f16)a.z, (f16)a.w,
               (f16)b.x, (f16)b.y, (f16)b.z, (f16)b.w};
    *(f16x8*)(dst + (size_t)off * 8) = r;
}

// ---------------------------------------------------------------------------
// QKV GEMM (R5-proven): 128x128 tile, BK=64, swizzled gload staging.
// mode 0: f16 out, [m][n] flat; mode 1: f16 out, transposed Vt [B,H,HD,S].
// ---------------------------------------------------------------------------
struct GemmArgs {
    const f16* X[3];
    const f16* W[3];
    const float* bias[3];
    void* out[3];
    float scale[3];
    int mode[3];
};

__global__ __launch_bounds__(256) void gemm_qkv(GemmArgs args) {
    __shared__ __align__(16) f16 sbuf[17408];
    f16* As = sbuf;
    f16* Bs = sbuf + 8192;

    const int z = blockIdx.z;
    const f16* __restrict__ X = args.X[z];
    const f16* __restrict__ W = args.W[z];
    const float* __restrict__ bias = args.bias[z];
    const float scale = args.scale[z];
    const int mode = args.mode[z];

    const int tid = threadIdx.x, w = tid >> 6, lane = tid & 63;
    const int lr = lane & 15, lg = lane >> 4;
    const int m0 = blockIdx.y * 128, n0 = blockIdx.x * 128;
    const int wm = (w >> 1) * 64, wn = (w & 1) * 64;

    const int dr = lane >> 3;
    const int schunk = (lane & 7) ^ dr;

    f32x4 acc[4][4] = {};

    for (int k0 = 0; k0 < Dn; k0 += 64) {
        __syncthreads();
#pragma unroll
        for (int j = 0; j < 4; ++j) {
            gload_lds16(X + (size_t)(m0 + w * 32 + j * 8 + dr) * Dn + k0 + schunk * 8,
                        &As[(w * 4 + j) * 512]);
            gload_lds16(W + (size_t)(n0 + w * 32 + j * 8 + dr) * Dn + k0 + schunk * 8,
                        &Bs[(w * 4 + j) * 512]);
        }
        __syncthreads();

#pragma unroll
        for (int half = 0; half < 2; ++half) {
            f16x8 a[4], b[4];
#pragma unroll
            for (int mi = 0; mi < 4; ++mi)
                a[mi] = *(const f16x8*)&As[swz(wm + mi * 16 + lr, half * 4 + lg)];
#pragma unroll
            for (int ni = 0; ni < 4; ++ni)
                b[ni] = *(const f16x8*)&Bs[swz(wn + ni * 16 + lr, half * 4 + lg)];
#pragma unroll
            for (int mi = 0; mi < 4; ++mi)
#pragma unroll
                for (int ni = 0; ni < 4; ++ni)
                    acc[mi][ni] = MFMA16(a[mi], b[ni], acc[mi][ni]);
        }
    }

    float bv[4];
#pragma unroll
    for (int ni = 0; ni < 4; ++ni) bv[ni] = bias[n0 + wn + ni * 16 + lr];

    __syncthreads();
    if (mode == 0) {
#pragma unroll
        for (int mi = 0; mi < 4; ++mi)
#pragma unroll
            for (int ni = 0; ni < 4; ++ni)
#pragma unroll
                for (int j = 0; j < 4; ++j)
                    sbuf[(wm + mi * 16 + lg * 4 + j) * 136 + wn + ni * 16 + lr] =
                        (f16)((acc[mi][ni][j] + bv[ni]) * scale);
        __syncthreads();
        f16* out = (f16*)args.out[z];
#pragma unroll
        for (int t = 0; t < 8; ++t) {
            const int idx = t * 256 + tid;
            const int r = idx >> 4, cc = (idx & 15) * 8;
            *(f16x8*)(out + (size_t)(m0 + r) * Dn + n0 + cc) = *(f16x8*)&sbuf[r * 136 + cc];
        }
    } else {
#pragma unroll
        for (int mi = 0; mi < 4; ++mi)
#pragma unroll
            for (int ni = 0; ni < 4; ++ni)
#pragma unroll
                for (int j = 0; j < 4; ++j)
                    sbuf[(wn + ni * 16 + lr) * 136 + wm + mi * 16 + lg * 4 + j] =
                        (f16)((acc[mi][ni][j] + bv[ni]) * scale);
        __syncthreads();
        f16* out = (f16*)args.out[z];
        const int b = m0 >> 11, s0 = m0 & (Sn - 1);
#pragma unroll
        for (int t = 0; t < 8; ++t) {
            const int idx = t * 256 + tid;
            const int nn = idx >> 4, cc = (idx & 15) * 8;
            const int n = n0 + nn;
            const int hh = n >> 6, d = n & 63;
            *(f16x8*)(out + (((size_t)(b * Hn + hh) * HDn + d) * Sn) + s0 + cc) =
                *(f16x8*)&sbuf[nn * 136 + cc];
        }
    }
}

// ---------------------------------------------------------------------------
// flash_ctx (unchanged from R11, passed): 512 thr, 128-row q-tiles, swapped
// QK^T (mfma(K,Q) -> C[key][q]), exp2 with log2e folded into Q scale.
// ---------------------------------------------------------------------------
__global__ __launch_bounds__(512) void flash_ctx(const f16* __restrict__ Qh,
                                                 const f16* __restrict__ Kh,
                                                 const f16* __restrict__ Vt,
                                                 f16* __restrict__ ctx,
                                                 float* __restrict__ rinv_g) {
    __shared__ __align__(16) f16 Qs[8192];   // [128][64] swizzled
    __shared__ __align__(16) f16 Ks[4096];   // [64 key][64 d] swizzled
    __shared__ __align__(16) f16 Vts[4096];  // [64 d][64 key] swizzled
    __shared__ __align__(16) f16 Ps[8 * 1152]; // per-wave [16 q][72 key]

    const int tid = threadIdx.x, w = tid >> 6, lane = tid & 63;
    const int lr = lane & 15, lg = lane >> 4;
    const int qt = (Sn / 128 - 1) - blockIdx.x; // longest-first
    const int bh = blockIdx.y;
    const int b = bh >> 4, h = bh & 15;

    const int dr = lane >> 3;
    const int schunk = (lane & 7) ^ dr;

    const f16* Qb = Qh + (size_t)b * Sn * Dn + h * HDn;
    const f16* Kb = Kh + (size_t)b * Sn * Dn + h * HDn;
    const f16* Vtb = Vt + (size_t)bh * HDn * Sn;

#pragma unroll
    for (int i = 0; i < 2; ++i)
        gload_lds16(Qb + (size_t)(qt * 128 + w * 16 + i * 8 + dr) * Dn + schunk * 8,
                    &Qs[(w * 16 + i * 8) * 64]);
    __syncthreads();
    f16x8 qa0 = *(const f16x8*)&Qs[swz(w * 16 + lr, lg)];
    f16x8 qa1 = *(const f16x8*)&Qs[swz(w * 16 + lr, 4 + lg)];

    const int qg = qt * 128 + w * 16 + lr;   // this lane's q row (global)
    const int qgmin = qt * 128 + w * 16;     // wave-uniform min q
    float lsum = 0.f;
    f32x4 octx[4] = {};
    const int ktmax = 2 * qt + 1;

    for (int kt = 0; kt <= ktmax; ++kt) {
        __syncthreads();
        gload_lds16(Kb + (size_t)(kt * 64 + w * 8 + dr) * Dn + schunk * 8, &Ks[w * 512]);
        gload_lds16(Vtb + (size_t)(w * 8 + dr) * Sn + kt * 64 + schunk * 8, &Vts[w * 512]);
        __syncthreads();

#pragma unroll
        for (int nf = 0; nf < 4; ++nf) {
            const int kbase = kt * 64 + nf * 16;
            f16x4* pdst = (f16x4*)&Ps[w * 1152 + lr * 72 + nf * 16 + lg * 4];
            if (kbase > qgmin + 15) {           // fragment fully masked
                *pdst = (f16x4){(f16)0.f, (f16)0.f, (f16)0.f, (f16)0.f};
                continue;
            }
            f16x8 kb0 = *(const f16x8*)&Ks[swz(nf * 16 + lr, lg)];
            f16x8 kb1 = *(const f16x8*)&Ks[swz(nf * 16 + lr, 4 + lg)];
            f32x4 a = {};
            a = MFMA16(kb0, qa0, a);            // C[key][q]
            a = MFMA16(kb1, qa1, a);
            float p[4];
            if (kbase + 15 <= qgmin) {          // fully unmasked (wave-uniform)
#pragma unroll
                for (int j = 0; j < 4; ++j) p[j] = __builtin_amdgcn_exp2f(a[j]);
            } else {
#pragma unroll
                for (int j = 0; j < 4; ++j) {
                    const int kg = kbase + lg * 4 + j;
                    p[j] = (kg > qg) ? 0.f : __builtin_amdgcn_exp2f(a[j]);
                }
            }
            lsum += (p[0] + p[1]) + (p[2] + p[3]);
            *pdst = (f16x4){(f16)p[0], (f16)p[1], (f16)p[2], (f16)p[3]};
        }

        f16x8 pa0 = *(const f16x8*)&Ps[w * 1152 + lr * 72 + lg * 8];
        f16x8 pa1 = *(const f16x8*)&Ps[w * 1152 + lr * 72 + 32 + lg * 8];
#pragma unroll
        for (int df = 0; df < 4; ++df) {
            octx[df] = MFMA16(pa0, *(const f16x8*)&Vts[swz(df * 16 + lr, lg)], octx[df]);
            octx[df] = MFMA16(pa1, *(const f16x8*)&Vts[swz(df * 16 + lr, 4 + lg)], octx[df]);
        }
    }

    lsum += __shfl_xor(lsum, 16);
    lsum += __shfl_xor(lsum, 32);
    const float rv = 1.0f / lsum;

    if (lg == 0)
        rinv_g[(size_t)bh * Sn + qt * 128 + w * 16 + lr] = rv;

    float rvj[4];
#pragma unroll
    for (int j = 0; j < 4; ++j) rvj[j] = __shfl(rv, lg * 4 + j);

#pragma unroll
    for (int df = 0; df < 4; ++df)
#pragma unroll
        for (int j = 0; j < 4; ++j) {
            const int sq = qt * 128 + w * 16 + lg * 4 + j;
            ctx[((size_t)b * Sn + sq) * Dn + h * HDn + df * 16 + lr] =
                (f16)(octx[df][j] * rvj[j]);
        }
}

// ---------------------------------------------------------------------------
// Fused tail: blocks 0..255 = oproj GEMM; blocks 256..1535 = attn writer.
// Writer: swapped QK^T + per-warp f32 LDS bounce [16][68] -> coalesced
// readback (rr=lane>>2, cb=(lane&3)*16): 64B/lane, 256B per 4-lane group.
// (R11's direct stores were 16B/lane at 8KB stride - the regression.)
// ---------------------------------------------------------------------------
__global__ __launch_bounds__(256) void tail_fused(const f16* __restrict__ Qh,
                                                  const f16* __restrict__ Kh,
                                                  const float* __restrict__ rinv_g,
                                                  float* __restrict__ attn,
                                                  const f16* __restrict__ ctxX,
                                                  const f16* __restrict__ Wo,
                                                  const float* __restrict__ bo,
                                                  float* __restrict__ out_f) {
    __shared__ __align__(16) f16 lds_[16896]; // 33792 B

    const int tid = threadIdx.x, w = tid >> 6, lane = tid & 63;
    const int lr = lane & 15, lg = lane >> 4;
    const int dr = lane >> 3;
    const int schunk = (lane & 7) ^ dr;

    if (blockIdx.x < 256) {
        // ---------------- output projection (R5-proven path) ----------------
        f16* As = lds_;
        f16* Bs = lds_ + 8192;
        const int n0 = (blockIdx.x & 7) * 128, m0 = (blockIdx.x >> 3) * 128;
        const int wm = (w >> 1) * 64, wn = (w & 1) * 64;

        f32x4 acc[4][4] = {};
        for (int k0 = 0; k0 < Dn; k0 += 64) {
            __syncthreads();
#pragma unroll
            for (int j = 0; j < 4; ++j) {
                gload_lds16(ctxX + (size_t)(m0 + w * 32 + j * 8 + dr) * Dn + k0 + schunk * 8,
                            &As[(w * 4 + j) * 512]);
                gload_lds16(Wo + (size_t)(n0 + w * 32 + j * 8 + dr) * Dn + k0 + schunk * 8,
                            &Bs[(w * 4 + j) * 512]);
            }
            __syncthreads();
#pragma unroll
            for (int half = 0; half < 2; ++half) {
                f16x8 a[4], b[4];
#pragma unroll
                for (int mi = 0; mi < 4; ++mi)
                    a[mi] = *(const f16x8*)&As[swz(wm + mi * 16 + lr, half * 4 + lg)];
#pragma unroll
                for (int ni = 0; ni < 4; ++ni)
                    b[ni] = *(const f16x8*)&Bs[swz(wn + ni * 16 + lr, half * 4 + lg)];
#pragma unroll
                for (int mi = 0; mi < 4; ++mi)
#pragma unroll
                    for (int ni = 0; ni < 4; ++ni)
                        acc[mi][ni] = MFMA16(a[mi], b[ni], acc[mi][ni]);
            }
        }
        float bv[4];
#pragma unroll
        for (int ni = 0; ni < 4; ++ni) bv[ni] = bo[n0 + wn + ni * 16 + lr];
#pragma unroll
        for (int mi = 0; mi < 4; ++mi)
#pragma unroll
            for (int ni = 0; ni < 4; ++ni)
#pragma unroll
                for (int j = 0; j < 4; ++j)
                    out_f[(size_t)(m0 + wm + mi * 16 + lg * 4 + j) * Dn + n0 + wn + ni * 16 + lr] =
                        acc[mi][ni][j] + bv[ni];
        return;
    }

    // ---------------- attn matrix writer ----------------
    const int bid = blockIdx.x - 256;
    const int qt = 31 - (bid & 31); // longest-first
    const int bh = bid >> 5;
    const int b = bh >> 4, h = bh & 15;

    f16* Qs = lds_;                        // [64][64] swizzled (8 KB)
    f16* Ks = lds_ + 4096;                 // [64][64] swizzled (8 KB)
    float* Psf = (float*)(lds_ + 8192);    // per-warp [16][68] f32 (17408 B)

    const f16* Qb = Qh + (size_t)b * Sn * Dn + h * HDn;
    const f16* Kb = Kh + (size_t)b * Sn * Dn + h * HDn;
    float* attn_base = attn + ((size_t)bh * Sn + qt * 64) * Sn;

    const float rv = rinv_g[(size_t)bh * Sn + qt * 64 + w * 16 + lr];
    const int qg = qt * 64 + w * 16 + lr;
    const int qgmin = qt * 64 + w * 16;

#pragma unroll
    for (int i = 0; i < 2; ++i)
        gload_lds16(Qb + (size_t)(qt * 64 + w * 16 + i * 8 + dr) * Dn + schunk * 8,
                    &Qs[(w * 16 + i * 8) * 64]);
    __syncthreads();
    f16x8 qa0 = *(const f16x8*)&Qs[swz(w * 16 + lr, lg)];
    f16x8 qa1 = *(const f16x8*)&Qs[swz(w * 16 + lr, 4 + lg)];

    const int rr = lane >> 2, cb = (lane & 3) * 16; // readback coords
    float* psw = Psf + w * 1088;                     // this warp's [16][68]

    for (int kt = 0; kt <= qt; ++kt) {
        __syncthreads();
#pragma unroll
        for (int i = 0; i < 2; ++i)
            gload_lds16(Kb + (size_t)(kt * 64 + w * 16 + i * 8 + dr) * Dn + schunk * 8,
                        &Ks[(w * 16 + i * 8) * 64]);
        __syncthreads();

#pragma unroll
        for (int nf = 0; nf < 4; ++nf) {
            const int kbase = kt * 64 + nf * 16;
            float4 o = {0.f, 0.f, 0.f, 0.f};
            if (kbase <= qgmin + 15) {
                f16x8 kb0 = *(const f16x8*)&Ks[swz(nf * 16 + lr, lg)];
                f16x8 kb1 = *(const f16x8*)&Ks[swz(nf * 16 + lr, 4 + lg)];
                f32x4 a = {};
                a = MFMA16(kb0, qa0, a);            // C[key][q]
                a = MFMA16(kb1, qa1, a);
                if (kbase + 15 <= qgmin) {          // fully unmasked
                    o.x = __builtin_amdgcn_exp2f(a[0]) * rv;
                    o.y = __builtin_amdgcn_exp2f(a[1]) * rv;
                    o.z = __builtin_amdgcn_exp2f(a[2]) * rv;
                    o.w = __builtin_amdgcn_exp2f(a[3]) * rv;
                } else {
                    const int k0g = kbase + lg * 4;
                    o.x = (k0g + 0 > qg) ? 0.f : __builtin_amdgcn_exp2f(a[0]) * rv;
                    o.y = (k0g + 1 > qg) ? 0.f : __builtin_amdgcn_exp2f(a[1]) * rv;
                    o.z = (k0g + 2 > qg) ? 0.f : __builtin_amdgcn_exp2f(a[2]) * rv;
                    o.w = (k0g + 3 > qg) ? 0.f : __builtin_amdgcn_exp2f(a[3]) * rv;
                }
            }
            *(float4*)&psw[lr * 68 + nf * 16 + lg * 4] = o; // 2-way bank max
        }

        // warp-local readback: row rr, 64B per lane; 4 lanes = 256B row run
        {
            const float* src = psw + rr * 68 + cb;
            float* dst = attn_base + (size_t)(w * 16 + rr) * Sn + kt * 64 + cb;
            float4 v0 = *(const float4*)(src + 0);
            float4 v1 = *(const float4*)(src + 4);
            float4 v2 = *(const float4*)(src + 8);
            float4 v3 = *(const float4*)(src + 12);
            ((float4*)dst)[0] = v0;
            ((float4*)dst)[1] = v1;
            ((float4*)dst)[2] = v2;
            ((float4*)dst)[3] = v3;
        }
    }

    // zero stripe beyond the diagonal tile
    const int colstart = (qt + 1) * 64;
    const int width4 = (Sn - colstart) >> 2;
    const float4 z = {0.f, 0.f, 0.f, 0.f};
    for (int r = 0; r < 64; ++r) {
        float4* dst = (float4*)(attn_base + (size_t)r * Sn + colstart);
        for (int c = tid; c < width4; c += 256) dst[c] = z;
    }
}

// ---------------------------------------------------------------------------
extern "C" void kernel_launch(void* const* d_in, const int* in_sizes, int n_in,
                              void* d_out, int out_size, void* d_ws, size_t ws_size,
                              hipStream_t stream) {
    const float* query = (const float*)d_in[0];
    const float* key   = (const float*)d_in[1];
    const float* value = (const float*)d_in[2];
    const float* Wq = (const float*)d_in[4];
    const float* bq = (const float*)d_in[5];
    const float* Wk = (const float*)d_in[6];
    const float* bk = (const float*)d_in[7];
    const float* Wv = (const float*)d_in[8];
    const float* bv = (const float*)d_in[9];
    const float* Wo = (const float*)d_in[10];
    const float* bo = (const float*)d_in[11];

    const size_t mk = (size_t)Mn * Dn;
    const size_t nk = (size_t)Dn * Dn;
    f16* p = (f16*)d_ws;
    f16 *Xq16 = p, *Xk16 = p + mk, *Xv16 = p + 2 * mk;
    f16 *Wq16 = p + 3 * mk, *Wk16 = Wq16 + nk, *Wv16 = Wq16 + 2 * nk, *Wo16 = Wq16 + 3 * nk;
    f16 *Qh = Wq16 + 4 * nk, *Kh = Qh + mk, *Vt = Qh + 2 * mk, *ctx = Qh + 3 * mk;
    float* rinv_g = (float*)(ctx + mk);

    float* out_f  = (float*)d_out;
    float* attn_f = out_f + (size_t)Bn * Sn * Dn;

    hipLaunchKernelGGL(convert_all, dim3(8192), dim3(256), 0, stream,
                       query, key, value, Wq, Wk, Wv, Wo,
                       Xq16, Xk16, Xv16, Wq16, Wk16, Wv16, Wo16);

    GemmArgs qkv;
    qkv.X[0] = Xq16; qkv.X[1] = Xk16; qkv.X[2] = Xv16;
    qkv.W[0] = Wq16; qkv.W[1] = Wk16; qkv.W[2] = Wv16;
    qkv.bias[0] = bq; qkv.bias[1] = bk; qkv.bias[2] = bv;
    qkv.out[0] = Qh; qkv.out[1] = Kh; qkv.out[2] = Vt;
    qkv.scale[0] = kQScale; qkv.scale[1] = 1.0f; qkv.scale[2] = 1.0f;
    qkv.mode[0] = 0; qkv.mode[1] = 0; qkv.mode[2] = 1;
    hipLaunchKernelGGL(gemm_qkv, dim3(Dn / 128, Mn / 128, 3), dim3(256), 0, stream, qkv);

    hipLaunchKernelGGL(flash_ctx, dim3(Sn / 128, Bn * Hn), dim3(512), 0, stream,
                       Qh, Kh, Vt, ctx, rinv_g);

    hipLaunchKernelGGL(tail_fused, dim3(256 + 1024), dim3(256), 0, stream,
                       Qh, Kh, rinv_g, attn_f, ctx, Wo16, bo, out_f);
}

// Round 13
// 293.948 us; speedup vs baseline: 1.0607x; 1.0607x over previous
//
#include <hip/hip_runtime.h>
#include <hip/hip_fp16.h>

typedef _Float16 f16;
typedef f16 f16x4 __attribute__((ext_vector_type(4)));
typedef f16 f16x8 __attribute__((ext_vector_type(8)));
typedef float f32x4 __attribute__((ext_vector_type(4)));

#define MFMA16(a, b, c) __builtin_amdgcn_mfma_f32_16x16x32_f16(a, b, c, 0, 0, 0)

static constexpr int Bn = 2, Sn = 2048, Dn = 1024, Hn = 16, HDn = 64;
static constexpr int Mn = Bn * Sn; // 4096
static constexpr float kQScale = 0.125f * 1.44269504088896f; // 1/sqrt(64) * log2(e)

__device__ inline void gload_lds16(const void* g, void* l) {
    __builtin_amdgcn_global_load_lds((const __attribute__((address_space(1))) void*)g,
                                     (__attribute__((address_space(3))) void*)l,
                                     16, 0, 0);
}

// T2 both-sides swizzle for [rows][64] f16 LDS tiles (row = 8 chunks of 16B).
__device__ inline int swz(int row, int chunk) {
    return row * 64 + ((chunk ^ (row & 7)) * 8);
}

// ---------------------------------------------------------------------------
// One-shot f32->f16 conversion of q,k,v and Wq,Wk,Wv,Wo.
// ---------------------------------------------------------------------------
__global__ __launch_bounds__(256) void convert_all(
    const float* __restrict__ q, const float* __restrict__ k, const float* __restrict__ v,
    const float* __restrict__ wq, const float* __restrict__ wk, const float* __restrict__ wv,
    const float* __restrict__ wo,
    f16* qo, f16* ko, f16* vo, f16* wqo, f16* wko, f16* wvo, f16* woo) {
    const int c = blockIdx.x * 256 + threadIdx.x;
    const float* src;
    f16* dst;
    int off;
    if (c < 3 * 524288) {
        const int t = c >> 19;
        off = c & 524287;
        src = (t == 0) ? q : (t == 1) ? k : v;
        dst = (t == 0) ? qo : (t == 1) ? ko : vo;
    } else {
        const int c2 = c - 3 * 524288;
        const int t = c2 >> 17;
        off = c2 & 131071;
        src = (t == 0) ? wq : (t == 1) ? wk : (t == 2) ? wv : wo;
        dst = (t == 0) ? wqo : (t == 1) ? wko : (t == 2) ? wvo : woo;
    }
    const float4 a = ((const float4*)src)[off * 2];
    const float4 b = ((const float4*)src)[off * 2 + 1];
    f16x8 r = {(f16)a.x, (f16)a.y, (f16)a.z, (f16)a.w,
               (f16)b.x, (f16)b.y, (f16)b.z, (f16)b.w};
    *(f16x8*)(dst + (size_t)off * 8) = r;
}

// ---------------------------------------------------------------------------
// QKV GEMM (R5-proven): 128x128 tile, BK=64, swizzled gload staging.
// mode 0: f16 out, [m][n] flat; mode 1: f16 out, transposed Vt [B,H,HD,S].
// ---------------------------------------------------------------------------
struct GemmArgs {
    const f16* X[3];
    const f16* W[3];
    const float* bias[3];
    void* out[3];
    float scale[3];
    int mode[3];
};

__global__ __launch_bounds__(256) void gemm_qkv(GemmArgs args) {
    __shared__ __align__(16) f16 sbuf[17408];
    f16* As = sbuf;
    f16* Bs = sbuf + 8192;

    const int z = blockIdx.z;
    const f16* __restrict__ X = args.X[z];
    const f16* __restrict__ W = args.W[z];
    const float* __restrict__ bias = args.bias[z];
    const float scale = args.scale[z];
    const int mode = args.mode[z];

    const int tid = threadIdx.x, w = tid >> 6, lane = tid & 63;
    const int lr = lane & 15, lg = lane >> 4;
    const int m0 = blockIdx.y * 128, n0 = blockIdx.x * 128;
    const int wm = (w >> 1) * 64, wn = (w & 1) * 64;

    const int dr = lane >> 3;
    const int schunk = (lane & 7) ^ dr;

    f32x4 acc[4][4] = {};

    for (int k0 = 0; k0 < Dn; k0 += 64) {
        __syncthreads();
#pragma unroll
        for (int j = 0; j < 4; ++j) {
            gload_lds16(X + (size_t)(m0 + w * 32 + j * 8 + dr) * Dn + k0 + schunk * 8,
                        &As[(w * 4 + j) * 512]);
            gload_lds16(W + (size_t)(n0 + w * 32 + j * 8 + dr) * Dn + k0 + schunk * 8,
                        &Bs[(w * 4 + j) * 512]);
        }
        __syncthreads();

#pragma unroll
        for (int half = 0; half < 2; ++half) {
            f16x8 a[4], b[4];
#pragma unroll
            for (int mi = 0; mi < 4; ++mi)
                a[mi] = *(const f16x8*)&As[swz(wm + mi * 16 + lr, half * 4 + lg)];
#pragma unroll
            for (int ni = 0; ni < 4; ++ni)
                b[ni] = *(const f16x8*)&Bs[swz(wn + ni * 16 + lr, half * 4 + lg)];
#pragma unroll
            for (int mi = 0; mi < 4; ++mi)
#pragma unroll
                for (int ni = 0; ni < 4; ++ni)
                    acc[mi][ni] = MFMA16(a[mi], b[ni], acc[mi][ni]);
        }
    }

    float bv[4];
#pragma unroll
    for (int ni = 0; ni < 4; ++ni) bv[ni] = bias[n0 + wn + ni * 16 + lr];

    __syncthreads();
    if (mode == 0) {
#pragma unroll
        for (int mi = 0; mi < 4; ++mi)
#pragma unroll
            for (int ni = 0; ni < 4; ++ni)
#pragma unroll
                for (int j = 0; j < 4; ++j)
                    sbuf[(wm + mi * 16 + lg * 4 + j) * 136 + wn + ni * 16 + lr] =
                        (f16)((acc[mi][ni][j] + bv[ni]) * scale);
        __syncthreads();
        f16* out = (f16*)args.out[z];
#pragma unroll
        for (int t = 0; t < 8; ++t) {
            const int idx = t * 256 + tid;
            const int r = idx >> 4, cc = (idx & 15) * 8;
            *(f16x8*)(out + (size_t)(m0 + r) * Dn + n0 + cc) = *(f16x8*)&sbuf[r * 136 + cc];
        }
    } else {
#pragma unroll
        for (int mi = 0; mi < 4; ++mi)
#pragma unroll
            for (int ni = 0; ni < 4; ++ni)
#pragma unroll
                for (int j = 0; j < 4; ++j)
                    sbuf[(wn + ni * 16 + lr) * 136 + wm + mi * 16 + lg * 4 + j] =
                        (f16)((acc[mi][ni][j] + bv[ni]) * scale);
        __syncthreads();
        f16* out = (f16*)args.out[z];
        const int b = m0 >> 11, s0 = m0 & (Sn - 1);
#pragma unroll
        for (int t = 0; t < 8; ++t) {
            const int idx = t * 256 + tid;
            const int nn = idx >> 4, cc = (idx & 15) * 8;
            const int n = n0 + nn;
            const int hh = n >> 6, d = n & 63;
            *(f16x8*)(out + (((size_t)(b * Hn + hh) * HDn + d) * Sn) + s0 + cc) =
                *(f16x8*)&sbuf[nn * 136 + cc];
        }
    }
}

// ---------------------------------------------------------------------------
// flash_ctx: 512 thr (8 waves x 16 q-rows), 128-row q-tiles, single pass.
// Swapped QK^T (mfma(K,Q) -> C[key][q]); exp2 with log2e folded into Q scale.
// BRANCHLESS inner loop (R11's wave-uniform fragment branches serialized the
// ds_read->MFMA chains; straight-line lets the compiler batch all 8 ds_reads
// and pipeline - the R5-flash property, now with 4x fewer VALU/LDS ops).
// ---------------------------------------------------------------------------
__global__ __launch_bounds__(512) void flash_ctx(const f16* __restrict__ Qh,
                                                 const f16* __restrict__ Kh,
                                                 const f16* __restrict__ Vt,
                                                 f16* __restrict__ ctx,
                                                 float* __restrict__ rinv_g) {
    __shared__ __align__(16) f16 Qs[8192];   // [128][64] swizzled
    __shared__ __align__(16) f16 Ks[4096];   // [64 key][64 d] swizzled
    __shared__ __align__(16) f16 Vts[4096];  // [64 d][64 key] swizzled
    __shared__ __align__(16) f16 Ps[8 * 1152]; // per-wave [16 q][72 key]

    const int tid = threadIdx.x, w = tid >> 6, lane = tid & 63;
    const int lr = lane & 15, lg = lane >> 4;
    const int qt = (Sn / 128 - 1) - blockIdx.x; // longest-first
    const int bh = blockIdx.y;
    const int b = bh >> 4, h = bh & 15;

    const int dr = lane >> 3;
    const int schunk = (lane & 7) ^ dr;

    const f16* Qb = Qh + (size_t)b * Sn * Dn + h * HDn;
    const f16* Kb = Kh + (size_t)b * Sn * Dn + h * HDn;
    const f16* Vtb = Vt + (size_t)bh * HDn * Sn;

#pragma unroll
    for (int i = 0; i < 2; ++i)
        gload_lds16(Qb + (size_t)(qt * 128 + w * 16 + i * 8 + dr) * Dn + schunk * 8,
                    &Qs[(w * 16 + i * 8) * 64]);
    __syncthreads();
    f16x8 qa0 = *(const f16x8*)&Qs[swz(w * 16 + lr, lg)];
    f16x8 qa1 = *(const f16x8*)&Qs[swz(w * 16 + lr, 4 + lg)];

    const int qg = qt * 128 + w * 16 + lr;   // this lane's q row (global)
    float lsum = 0.f;
    f32x4 octx[4] = {};
    const int ktmax = 2 * qt + 1;

    for (int kt = 0; kt <= ktmax; ++kt) {
        __syncthreads();
        gload_lds16(Kb + (size_t)(kt * 64 + w * 8 + dr) * Dn + schunk * 8, &Ks[w * 512]);
        gload_lds16(Vtb + (size_t)(w * 8 + dr) * Sn + kt * 64 + schunk * 8, &Vts[w * 512]);
        __syncthreads();

#pragma unroll
        for (int nf = 0; nf < 4; ++nf) {
            f16x8 kb0 = *(const f16x8*)&Ks[swz(nf * 16 + lr, lg)];
            f16x8 kb1 = *(const f16x8*)&Ks[swz(nf * 16 + lr, 4 + lg)];
            f32x4 a = {};
            a = MFMA16(kb0, qa0, a);            // C[key][q]
            a = MFMA16(kb1, qa1, a);
            const int k0 = kt * 64 + nf * 16 + lg * 4;
            const float p0 = (k0 + 0 <= qg) ? __builtin_amdgcn_exp2f(a[0]) : 0.f;
            const float p1 = (k0 + 1 <= qg) ? __builtin_amdgcn_exp2f(a[1]) : 0.f;
            const float p2 = (k0 + 2 <= qg) ? __builtin_amdgcn_exp2f(a[2]) : 0.f;
            const float p3 = (k0 + 3 <= qg) ? __builtin_amdgcn_exp2f(a[3]) : 0.f;
            lsum += (p0 + p1) + (p2 + p3);
            *(f16x4*)&Ps[w * 1152 + lr * 72 + nf * 16 + lg * 4] =
                (f16x4){(f16)p0, (f16)p1, (f16)p2, (f16)p3};
        }

        f16x8 pa0 = *(const f16x8*)&Ps[w * 1152 + lr * 72 + lg * 8];
        f16x8 pa1 = *(const f16x8*)&Ps[w * 1152 + lr * 72 + 32 + lg * 8];
#pragma unroll
        for (int df = 0; df < 4; ++df) {
            octx[df] = MFMA16(pa0, *(const f16x8*)&Vts[swz(df * 16 + lr, lg)], octx[df]);
            octx[df] = MFMA16(pa1, *(const f16x8*)&Vts[swz(df * 16 + lr, 4 + lg)], octx[df]);
        }
    }

    lsum += __shfl_xor(lsum, 16);
    lsum += __shfl_xor(lsum, 32);
    const float rv = 1.0f / lsum;

    if (lg == 0)
        rinv_g[(size_t)bh * Sn + qt * 128 + w * 16 + lr] = rv;

    float rvj[4];
#pragma unroll
    for (int j = 0; j < 4; ++j) rvj[j] = __shfl(rv, lg * 4 + j);

#pragma unroll
    for (int df = 0; df < 4; ++df)
#pragma unroll
        for (int j = 0; j < 4; ++j) {
            const int sq = qt * 128 + w * 16 + lg * 4 + j;
            ctx[((size_t)b * Sn + sq) * Dn + h * HDn + df * 16 + lr] =
                (f16)(octx[df][j] * rvj[j]);
        }
}

// ---------------------------------------------------------------------------
// Fused tail: blocks 0..255 = oproj GEMM; blocks 256..1535 = attn writer.
// Writer: swapped QK^T, BRANCHLESS, direct float4 stores (R11 pattern: per
// store inst, 16 rows x 64B runs - same coalescing as a bounce, no LDS trip).
// ---------------------------------------------------------------------------
__global__ __launch_bounds__(256) void tail_fused(const f16* __restrict__ Qh,
                                                  const f16* __restrict__ Kh,
                                                  const float* __restrict__ rinv_g,
                                                  float* __restrict__ attn,
                                                  const f16* __restrict__ ctxX,
                                                  const f16* __restrict__ Wo,
                                                  const float* __restrict__ bo,
                                                  float* __restrict__ out_f) {
    __shared__ __align__(16) f16 lds_[16384]; // 32KB

    const int tid = threadIdx.x, w = tid >> 6, lane = tid & 63;
    const int lr = lane & 15, lg = lane >> 4;
    const int dr = lane >> 3;
    const int schunk = (lane & 7) ^ dr;

    if (blockIdx.x < 256) {
        // ---------------- output projection (R5-proven path) ----------------
        f16* As = lds_;
        f16* Bs = lds_ + 8192;
        const int n0 = (blockIdx.x & 7) * 128, m0 = (blockIdx.x >> 3) * 128;
        const int wm = (w >> 1) * 64, wn = (w & 1) * 64;

        f32x4 acc[4][4] = {};
        for (int k0 = 0; k0 < Dn; k0 += 64) {
            __syncthreads();
#pragma unroll
            for (int j = 0; j < 4; ++j) {
                gload_lds16(ctxX + (size_t)(m0 + w * 32 + j * 8 + dr) * Dn + k0 + schunk * 8,
                            &As[(w * 4 + j) * 512]);
                gload_lds16(Wo + (size_t)(n0 + w * 32 + j * 8 + dr) * Dn + k0 + schunk * 8,
                            &Bs[(w * 4 + j) * 512]);
            }
            __syncthreads();
#pragma unroll
            for (int half = 0; half < 2; ++half) {
                f16x8 a[4], b[4];
#pragma unroll
                for (int mi = 0; mi < 4; ++mi)
                    a[mi] = *(const f16x8*)&As[swz(wm + mi * 16 + lr, half * 4 + lg)];
#pragma unroll
                for (int ni = 0; ni < 4; ++ni)
                    b[ni] = *(const f16x8*)&Bs[swz(wn + ni * 16 + lr, half * 4 + lg)];
#pragma unroll
                for (int mi = 0; mi < 4; ++mi)
#pragma unroll
                    for (int ni = 0; ni < 4; ++ni)
                        acc[mi][ni] = MFMA16(a[mi], b[ni], acc[mi][ni]);
            }
        }
        float bv[4];
#pragma unroll
        for (int ni = 0; ni < 4; ++ni) bv[ni] = bo[n0 + wn + ni * 16 + lr];
#pragma unroll
        for (int mi = 0; mi < 4; ++mi)
#pragma unroll
            for (int ni = 0; ni < 4; ++ni)
#pragma unroll
                for (int j = 0; j < 4; ++j)
                    out_f[(size_t)(m0 + wm + mi * 16 + lg * 4 + j) * Dn + n0 + wn + ni * 16 + lr] =
                        acc[mi][ni][j] + bv[ni];
        return;
    }

    // ---------------- attn matrix writer ----------------
    const int bid = blockIdx.x - 256;
    const int qt = 31 - (bid & 31); // longest-first
    const int bh = bid >> 5;
    const int b = bh >> 4, h = bh & 15;

    f16* Qs = lds_;          // [64][64] swizzled
    f16* Ks = lds_ + 4096;   // [64][64] swizzled

    const f16* Qb = Qh + (size_t)b * Sn * Dn + h * HDn;
    const f16* Kb = Kh + (size_t)b * Sn * Dn + h * HDn;
    float* attn_base = attn + ((size_t)bh * Sn + qt * 64) * Sn;

    const float rv = rinv_g[(size_t)bh * Sn + qt * 64 + w * 16 + lr];
    const int qg = qt * 64 + w * 16 + lr;

#pragma unroll
    for (int i = 0; i < 2; ++i)
        gload_lds16(Qb + (size_t)(qt * 64 + w * 16 + i * 8 + dr) * Dn + schunk * 8,
                    &Qs[(w * 16 + i * 8) * 64]);
    __syncthreads();
    f16x8 qa0 = *(const f16x8*)&Qs[swz(w * 16 + lr, lg)];
    f16x8 qa1 = *(const f16x8*)&Qs[swz(w * 16 + lr, 4 + lg)];

    float* rowp = attn_base + (size_t)(w * 16 + lr) * Sn + lg * 4;

    for (int kt = 0; kt <= qt; ++kt) {
        __syncthreads();
#pragma unroll
        for (int i = 0; i < 2; ++i)
            gload_lds16(Kb + (size_t)(kt * 64 + w * 16 + i * 8 + dr) * Dn + schunk * 8,
                        &Ks[(w * 16 + i * 8) * 64]);
        __syncthreads();

#pragma unroll
        for (int nf = 0; nf < 4; ++nf) {
            f16x8 kb0 = *(const f16x8*)&Ks[swz(nf * 16 + lr, lg)];
            f16x8 kb1 = *(const f16x8*)&Ks[swz(nf * 16 + lr, 4 + lg)];
            f32x4 a = {};
            a = MFMA16(kb0, qa0, a);            // C[key][q]
            a = MFMA16(kb1, qa1, a);
            const int k0g = kt * 64 + nf * 16 + lg * 4;
            float4 o;
            o.x = (k0g + 0 <= qg) ? __builtin_amdgcn_exp2f(a[0]) * rv : 0.f;
            o.y = (k0g + 1 <= qg) ? __builtin_amdgcn_exp2f(a[1]) * rv : 0.f;
            o.z = (k0g + 2 <= qg) ? __builtin_amdgcn_exp2f(a[2]) * rv : 0.f;
            o.w = (k0g + 3 <= qg) ? __builtin_amdgcn_exp2f(a[3]) * rv : 0.f;
            *(float4*)(rowp + kt * 64 + nf * 16) = o;
        }
    }

    // zero stripe beyond the diagonal tile
    const int colstart = (qt + 1) * 64;
    const int width4 = (Sn - colstart) >> 2;
    const float4 z = {0.f, 0.f, 0.f, 0.f};
    for (int r = 0; r < 64; ++r) {
        float4* dst = (float4*)(attn_base + (size_t)r * Sn + colstart);
        for (int c = tid; c < width4; c += 256) dst[c] = z;
    }
}

// ---------------------------------------------------------------------------
extern "C" void kernel_launch(void* const* d_in, const int* in_sizes, int n_in,
                              void* d_out, int out_size, void* d_ws, size_t ws_size,
                              hipStream_t stream) {
    const float* query = (const float*)d_in[0];
    const float* key   = (const float*)d_in[1];
    const float* value = (const float*)d_in[2];
    const float* Wq = (const float*)d_in[4];
    const float* bq = (const float*)d_in[5];
    const float* Wk = (const float*)d_in[6];
    const float* bk = (const float*)d_in[7];
    const float* Wv = (const float*)d_in[8];
    const float* bv = (const float*)d_in[9];
    const float* Wo = (const float*)d_in[10];
    const float* bo = (const float*)d_in[11];

    const size_t mk = (size_t)Mn * Dn;
    const size_t nk = (size_t)Dn * Dn;
    f16* p = (f16*)d_ws;
    f16 *Xq16 = p, *Xk16 = p + mk, *Xv16 = p + 2 * mk;
    f16 *Wq16 = p + 3 * mk, *Wk16 = Wq16 + nk, *Wv16 = Wq16 + 2 * nk, *Wo16 = Wq16 + 3 * nk;
    f16 *Qh = Wq16 + 4 * nk, *Kh = Qh + mk, *Vt = Qh + 2 * mk, *ctx = Qh + 3 * mk;
    float* rinv_g = (float*)(ctx + mk);

    float* out_f  = (float*)d_out;
    float* attn_f = out_f + (size_t)Bn * Sn * Dn;

    hipLaunchKernelGGL(convert_all, dim3(8192), dim3(256), 0, stream,
                       query, key, value, Wq, Wk, Wv, Wo,
                       Xq16, Xk16, Xv16, Wq16, Wk16, Wv16, Wo16);

    GemmArgs qkv;
    qkv.X[0] = Xq16; qkv.X[1] = Xk16; qkv.X[2] = Xv16;
    qkv.W[0] = Wq16; qkv.W[1] = Wk16; qkv.W[2] = Wv16;
    qkv.bias[0] = bq; qkv.bias[1] = bk; qkv.bias[2] = bv;
    qkv.out[0] = Qh; qkv.out[1] = Kh; qkv.out[2] = Vt;
    qkv.scale[0] = kQScale; qkv.scale[1] = 1.0f; qkv.scale[2] = 1.0f;
    qkv.mode[0] = 0; qkv.mode[1] = 0; qkv.mode[2] = 1;
    hipLaunchKernelGGL(gemm_qkv, dim3(Dn / 128, Mn / 128, 3), dim3(256), 0, stream, qkv);

    hipLaunchKernelGGL(flash_ctx, dim3(Sn / 128, Bn * Hn), dim3(512), 0, stream,
                       Qh, Kh, Vt, ctx, rinv_g);

    hipLaunchKernelGGL(tail_fused, dim3(256 + 1024), dim3(256), 0, stream,
                       Qh, Kh, rinv_g, attn_f, ctx, Wo16, bo, out_f);
}